// Round 2
// baseline (495.079 us; speedup 1.0000x reference)
//
#include <hip/hip_runtime.h>

// TorchSAT: summed-area-table rectangle sampling.
// sat: (512,512,288) fp32, x: (N,4) fp32 -> out: (N,288) fp32.
// One wave per output row; all per-row case logic is wave-uniform.
//
// R4: separable cross-product decomposition (u-list (x) v-list), avg issued
//     samples 9 -> 6.25, single load batch per case. Result: neutral ->
//     kernel is memory-SERVICE bound, not issue bound.
// R5: locality sort. x is uniform-random, so adjacent waves share zero sat
//     locality. Counting-sort queries by the e-corner texel block
//     key = (i_u(neu)<<3) | (i_v(nev)>>6)  (4096 buckets, ~32 queries each)
//     so consecutive waves gather from the same ~73 KB sat stripe ->
//     L1/L2-hot + HBM-sequential for the +e corner pair (~40% of traffic).
//     Pipeline: zero -> hist -> scan -> scatter(perm) -> main(perm).
//     Values are bit-identical (only wave->query order changes).

constexpr int Hdim = 512;
constexpr int Wdim = 512;
constexpr int Cdim = 288;
constexpr int NQB  = 4096;  // sort buckets

typedef float f32x4 __attribute__((ext_vector_type(4)));

// ---------- shared query math ----------

// Per-axis corner prep: coordinate -> texel index + effective sign (0 if OOB).
__device__ __forceinline__ void axis_prep(float u, float s, int& idx, float& sgn) {
    int i = (int)floorf(u * 512.0f - 0.5f);
    bool ok = (unsigned)i < 512u;
    idx = ok ? i : 0;
    sgn = ok ? s : 0.0f;
}

// Sort key: texel block of the normalized e-corner. Must be identical in
// k_hist and k_scatter.
__device__ __forceinline__ int query_key(float cu, float cv, float d0, float d1) {
    float su = cu - d0 * 0.5f, eu = cu + d0 * 0.5f;
    float sv = cv - d1 * 0.5f, ev = cv + d1 * 0.5f;
    float neu = (d0 < 0.0f) ? su : eu;
    float nev = (d1 < 0.0f) ? sv : ev;
    neu -= floorf(neu);
    nev -= floorf(nev);
    int iu = (int)floorf(neu * 512.0f - 0.5f);
    int iv = (int)floorf(nev * 512.0f - 0.5f);
    iu = min(max(iu, 0), 511);
    iv = min(max(iv, 0), 511);
    return (iu << 3) | (iv >> 6);
}

// ---------- sort pipeline ----------

__global__ __launch_bounds__(256) void k_zero(int* hist) {
    int i = blockIdx.x * blockDim.x + threadIdx.x;
    if (i < 2 * NQB) hist[i] = 0;
}

__global__ __launch_bounds__(256) void k_hist(const float4* __restrict__ x, int n,
                                              int* __restrict__ hist) {
    for (int q = blockIdx.x * blockDim.x + threadIdx.x; q < n;
         q += gridDim.x * blockDim.x) {
        float4 xr = x[q];
        atomicAdd(&hist[query_key(xr.x, xr.y, xr.z, xr.w)], 1);
    }
}

// Single block, 256 threads: exclusive scan of hist[4096] -> offs[4096].
__global__ __launch_bounds__(256) void k_scan(const int* __restrict__ hist,
                                              int* __restrict__ offs) {
    __shared__ int part[256];
    int t = threadIdx.x;
    int base = t * 16;
    int local[16];
    int s = 0;
#pragma unroll
    for (int i = 0; i < 16; ++i) { local[i] = hist[base + i]; s += local[i]; }
    part[t] = s;
    __syncthreads();
    for (int d = 1; d < 256; d <<= 1) {
        int v = (t >= d) ? part[t - d] : 0;
        __syncthreads();
        part[t] += v;
        __syncthreads();
    }
    int run = part[t] - s;  // exclusive prefix of this thread's chunk
#pragma unroll
    for (int i = 0; i < 16; ++i) { offs[base + i] = run; run += local[i]; }
}

__global__ __launch_bounds__(256) void k_scatter(const float4* __restrict__ x, int n,
                                                 int* __restrict__ offs,
                                                 int* __restrict__ perm) {
    for (int q = blockIdx.x * blockDim.x + threadIdx.x; q < n;
         q += gridDim.x * blockDim.x) {
        float4 xr = x[q];
        int pos = atomicAdd(&offs[query_key(xr.x, xr.y, xr.z, xr.w)], 1);
        perm[pos] = q;
    }
}

// ---------- main kernel ----------

// Issue K samples' loads back-to-back (deep MLP), then accumulate.
template <int K>
__device__ __forceinline__ void gather(const float* __restrict__ sat,
                                       const int* off, const float* sgn,
                                       int lane, int widx,
                                       f32x4& a, f32x4& b) {
    f32x4 v[K], w[K];
#pragma unroll
    for (int k = 0; k < K; ++k) {
        int offk = __builtin_amdgcn_readfirstlane(off[k]);
        const f32x4* __restrict__ row = (const f32x4*)(sat + offk);
        v[k] = row[lane];
        w[k] = row[widx];
    }
#pragma unroll
    for (int k = 0; k < K; ++k) {
        float s = sgn[k];
        a += s * v[k];
        b += s * w[k];
    }
}

// Cross product of NU u-corners and NV v-corners -> NU*NV samples.
template <int NU, int NV>
__device__ __forceinline__ void run_case(const float* __restrict__ sat,
                                         const int* iu, const float* fu,
                                         const int* iv, const float* fv,
                                         int lane, int widx,
                                         f32x4& a, f32x4& b) {
    int off[NU * NV];
    float sgn[NU * NV];
#pragma unroll
    for (int i = 0; i < NU; ++i)
#pragma unroll
        for (int j = 0; j < NV; ++j) {
            off[i * NV + j] = (iu[i] * Wdim + iv[j]) * Cdim;
            sgn[i * NV + j] = fu[i] * fv[j];
        }
    gather<NU * NV>(sat, off, sgn, lane, widx, a, b);
}

__global__ __launch_bounds__(256) void sat_query_kernel(
    const float* __restrict__ sat, const float* __restrict__ x,
    float* __restrict__ out, int n, const int* __restrict__ perm) {
    int wave = (int)((blockIdx.x * blockDim.x + threadIdx.x) >> 6);
    int lane = (int)(threadIdx.x & 63);
    if (wave >= n) return;
    int qid = perm ? perm[wave] : wave;

    float4 xr = ((const float4*)x)[qid];
    float cu = xr.x, cv = xr.y, d0 = xr.z, d1 = xr.w;

    const float du = 1.0f / 512.0f;  // == dv (H == W == 512)

    float su = cu - d0 * 0.5f, eu = cu + d0 * 0.5f;
    float sv = cv - d1 * 0.5f, ev = cv + d1 * 0.5f;
    float nsu = (d0 < 0.0f) ? eu : su, neu = (d0 < 0.0f) ? su : eu;
    float nsv = (d1 < 0.0f) ? ev : sv, nev = (d1 < 0.0f) ? sv : ev;
    nsu -= floorf(nsu); neu -= floorf(neu);
    nsv -= floorf(nsv); nev -= floorf(nev);

    bool wx = nsu > neu;  // u-axis wraps
    bool wy = nsv > nev;  // v-axis wraps

    // Axis difference operators. Third entry (texel 511, always in-bounds)
    // participates only when that axis wraps.
    int iu[3]; float fu[3];
    axis_prep(neu,       1.0f, iu[0], fu[0]);
    axis_prep(nsu - du, -1.0f, iu[1], fu[1]);
    iu[2] = Hdim - 1; fu[2] = 1.0f;

    int iv[3]; float fv[3];
    axis_prep(nev,       1.0f, iv[0], fv[0]);
    axis_prep(nsv - du, -1.0f, iv[1], fv[1]);
    iv[2] = Wdim - 1; fv[2] = 1.0f;

    f32x4 acc_a = {0.f, 0.f, 0.f, 0.f};
    f32x4 acc_b = {0.f, 0.f, 0.f, 0.f};
    int widx = (lane & 7) + 64;  // in-row, replicated tail index

    if (!wx && !wy) {
        run_case<2, 2>(sat, iu, fu, iv, fv, lane, widx, acc_a, acc_b);
    } else if (wx && !wy) {
        run_case<3, 2>(sat, iu, fu, iv, fv, lane, widx, acc_a, acc_b);
    } else if (!wx && wy) {
        run_case<2, 3>(sat, iu, fu, iv, fv, lane, widx, acc_a, acc_b);
    } else {
        run_case<3, 3>(sat, iu, fu, iv, fv, lane, widx, acc_a, acc_b);
    }

    // Streaming output: nontemporal so the 151 MB write stream doesn't evict
    // sat from Infinity Cache (sat is 302 MB vs 256 MB L3 -> retention matters).
    f32x4* __restrict__ orow = (f32x4*)(out + (size_t)qid * Cdim);
    __builtin_nontemporal_store(acc_a, orow + lane);
    if (lane < 8) __builtin_nontemporal_store(acc_b, orow + lane + 64);
}

extern "C" void kernel_launch(void* const* d_in, const int* in_sizes, int n_in,
                              void* d_out, int out_size, void* d_ws, size_t ws_size,
                              hipStream_t stream) {
    const float* sat = (const float*)d_in[0];
    const float* x   = (const float*)d_in[1];
    // d_in[2]=start_idx (-1), d_in[3]=len_idx: out_size == N*288 pins the
    // no-slice path, so they are ignored.
    float* out = (float*)d_out;
    int n = in_sizes[1] / 4;  // x is (N,4)

    int blocks = (n + 3) / 4;  // 4 waves (queries) per 256-thread block

    size_t need = (size_t)(2 * NQB + n) * sizeof(int);
    if (d_ws != nullptr && ws_size >= need) {
        int* hist = (int*)d_ws;
        int* offs = hist + NQB;
        int* perm = offs + NQB;
        int gsb = (n + 255) / 256;
        k_zero<<<dim3((2 * NQB + 255) / 256), dim3(256), 0, stream>>>(hist);
        k_hist<<<dim3(gsb), dim3(256), 0, stream>>>((const float4*)x, n, hist);
        k_scan<<<dim3(1), dim3(256), 0, stream>>>(hist, offs);
        k_scatter<<<dim3(gsb), dim3(256), 0, stream>>>((const float4*)x, n, offs, perm);
        sat_query_kernel<<<dim3(blocks), dim3(256), 0, stream>>>(sat, x, out, n, perm);
    } else {
        sat_query_kernel<<<dim3(blocks), dim3(256), 0, stream>>>(sat, x, out, n, nullptr);
    }
}

// Round 4
// 472.833 us; speedup vs baseline: 1.0470x; 1.0470x over previous
//
#include <hip/hip_runtime.h>

// TorchSAT: summed-area-table rectangle sampling.
// sat: (512,512,288) fp32, x: (N,4) fp32 -> out: (N,288) fp32.
// One wave per output row; all per-row case logic is wave-uniform.
//
// R4: separable cross-product decomposition (u-list (x) v-list), avg issued
//     samples 9 -> 6.25, single load batch per case. Neutral vs R3 ->
//     kernel is memory-SERVICE bound, not issue bound.
// R5: counting-sort queries for gather locality. REGRESSED (+23 us = sort
//     pipeline cost; ~0.5 queries/texel -> no row sharing to exploit, and
//     the perm scattered the output write stream). Reverted.
// R6: revert to R4 (measured best, 471.8 us). Infra failure on the bench;
// R7: resubmit unchanged. Kernel traffic is within a few percent of the
//     6.3 TB/s random-gather roofline: ~0.94 GB mandatory corner-row reads
//     + 151 MB NT writes ~= 173 us; kernel measures < 182 us (absent from
//     top-5 vs 182-us re-poison fills).

constexpr int Hdim = 512;
constexpr int Wdim = 512;
constexpr int Cdim = 288;

typedef float f32x4 __attribute__((ext_vector_type(4)));

// Per-axis corner prep: coordinate -> texel index + effective sign (0 if OOB).
// u in [-1/512, 1): idx = floor(u*512 - 0.5) in [-2, 511]; only low-side OOB
// is possible, caught by the unsigned compare.
__device__ __forceinline__ void axis_prep(float u, float s, int& idx, float& sgn) {
    int i = (int)floorf(u * 512.0f - 0.5f);
    bool ok = (unsigned)i < 512u;
    idx = ok ? i : 0;
    sgn = ok ? s : 0.0f;
}

// Issue K samples' loads back-to-back (deep MLP), then accumulate.
// Offsets are wave-uniform -> readfirstlane pins them to SGPRs so each load
// is global_load_dwordx4 with scalar base + lane byte-offset.
// widx = (lane&7)+64 keeps the 288-float tail load in-row and non-divergent;
// lanes >= 8 accumulate a dead acc_b that is never stored.
template <int K>
__device__ __forceinline__ void gather(const float* __restrict__ sat,
                                       const int* off, const float* sgn,
                                       int lane, int widx,
                                       f32x4& a, f32x4& b) {
    f32x4 v[K], w[K];
#pragma unroll
    for (int k = 0; k < K; ++k) {
        int offk = __builtin_amdgcn_readfirstlane(off[k]);
        const f32x4* __restrict__ row = (const f32x4*)(sat + offk);
        v[k] = row[lane];
        w[k] = row[widx];
    }
#pragma unroll
    for (int k = 0; k < K; ++k) {
        float s = sgn[k];
        a += s * v[k];
        b += s * w[k];
    }
}

// Cross product of NU u-corners and NV v-corners -> NU*NV samples.
template <int NU, int NV>
__device__ __forceinline__ void run_case(const float* __restrict__ sat,
                                         const int* iu, const float* fu,
                                         const int* iv, const float* fv,
                                         int lane, int widx,
                                         f32x4& a, f32x4& b) {
    int off[NU * NV];
    float sgn[NU * NV];
#pragma unroll
    for (int i = 0; i < NU; ++i)
#pragma unroll
        for (int j = 0; j < NV; ++j) {
            off[i * NV + j] = (iu[i] * Wdim + iv[j]) * Cdim;
            sgn[i * NV + j] = fu[i] * fv[j];
        }
    gather<NU * NV>(sat, off, sgn, lane, widx, a, b);
}

__global__ __launch_bounds__(256) void sat_query_kernel(
    const float* __restrict__ sat, const float* __restrict__ x,
    float* __restrict__ out, int n) {
    int wave = (int)((blockIdx.x * blockDim.x + threadIdx.x) >> 6);
    int lane = (int)(threadIdx.x & 63);
    if (wave >= n) return;

    float4 xr = ((const float4*)x)[wave];
    float cu = xr.x, cv = xr.y, d0 = xr.z, d1 = xr.w;

    const float du = 1.0f / 512.0f;  // == dv (H == W == 512)

    float su = cu - d0 * 0.5f, eu = cu + d0 * 0.5f;
    float sv = cv - d1 * 0.5f, ev = cv + d1 * 0.5f;
    float nsu = (d0 < 0.0f) ? eu : su, neu = (d0 < 0.0f) ? su : eu;
    float nsv = (d1 < 0.0f) ? ev : sv, nev = (d1 < 0.0f) ? sv : ev;
    nsu -= floorf(nsu); neu -= floorf(neu);
    nsv -= floorf(nsv); nev -= floorf(nev);

    bool wx = nsu > neu;  // u-axis wraps
    bool wy = nsv > nev;  // v-axis wraps

    // Axis difference operators. Third entry (texel 511, always in-bounds)
    // participates only when that axis wraps.
    int iu[3]; float fu[3];
    axis_prep(neu,       1.0f, iu[0], fu[0]);
    axis_prep(nsu - du, -1.0f, iu[1], fu[1]);
    iu[2] = Hdim - 1; fu[2] = 1.0f;

    int iv[3]; float fv[3];
    axis_prep(nev,       1.0f, iv[0], fv[0]);
    axis_prep(nsv - du, -1.0f, iv[1], fv[1]);
    iv[2] = Wdim - 1; fv[2] = 1.0f;

    f32x4 acc_a = {0.f, 0.f, 0.f, 0.f};
    f32x4 acc_b = {0.f, 0.f, 0.f, 0.f};
    int widx = (lane & 7) + 64;  // in-row, replicated tail index

    if (!wx && !wy) {
        run_case<2, 2>(sat, iu, fu, iv, fv, lane, widx, acc_a, acc_b);
    } else if (wx && !wy) {
        run_case<3, 2>(sat, iu, fu, iv, fv, lane, widx, acc_a, acc_b);
    } else if (!wx && wy) {
        run_case<2, 3>(sat, iu, fu, iv, fv, lane, widx, acc_a, acc_b);
    } else {
        run_case<3, 3>(sat, iu, fu, iv, fv, lane, widx, acc_a, acc_b);
    }

    // Streaming output: nontemporal so the 151 MB write stream doesn't evict
    // sat from Infinity Cache (sat is 302 MB vs 256 MB L3 -> retention matters).
    f32x4* __restrict__ orow = (f32x4*)(out + (size_t)wave * Cdim);
    __builtin_nontemporal_store(acc_a, orow + lane);
    if (lane < 8) __builtin_nontemporal_store(acc_b, orow + lane + 64);
}

extern "C" void kernel_launch(void* const* d_in, const int* in_sizes, int n_in,
                              void* d_out, int out_size, void* d_ws, size_t ws_size,
                              hipStream_t stream) {
    const float* sat = (const float*)d_in[0];
    const float* x   = (const float*)d_in[1];
    // d_in[2]=start_idx (-1), d_in[3]=len_idx: out_size == N*288 pins the
    // no-slice path, so they are ignored.
    float* out = (float*)d_out;
    int n = in_sizes[1] / 4;  // x is (N,4)

    int rows_per_block = 4;  // 256 threads = 4 waves
    int blocks = (n + rows_per_block - 1) / rows_per_block;
    sat_query_kernel<<<dim3(blocks), dim3(256), 0, stream>>>(sat, x, out, n);
}